// Round 3
// baseline (181.648 us; speedup 1.0000x reference)
//
#include <hip/hip_runtime.h>

#define GAMMA 0.99f
constexpr int T_DIM = 128;
constexpr int B_DIM = 512;
constexpr int Q_DIM = 50;
constexpr int NROW  = (T_DIM - 1) * B_DIM;   // 65024 loss rows (t<127)
constexpr int NPAIR = NROW * Q_DIM;          // 3251200 = 12700 * 256 exactly
constexpr int SLOT  = 52;                    // LDS row stride (208B, 16B-aligned)
constexpr int LROWS = 7;                     // rows per block: 256 idx can span 7

// ---------------------------------------------------------------------------
// K1: per-b affine coefficient chain.  ret[t,b,q] = alpha[t,b]*tv[n[t,b],b,q]
// + beta[t,b].  512 threads total, 127 serial steps each; coalesced loads.
// ---------------------------------------------------------------------------
__global__ void __launch_bounds__(64) coeff_kernel(
    const float* __restrict__ reward,
    const int*   __restrict__ step_type,
    const float* __restrict__ discount,
    float* __restrict__ alpha,
    float* __restrict__ beta,
    int*   __restrict__ anchor) {
  const int b = blockIdx.x * 64 + threadIdx.x;   // 8 blocks x 64 -> b in [0,512)
  float a = 1.0f, be = 0.0f;
  int   n = T_DIM - 1;
  for (int t = T_DIM - 2; t >= 0; --t) {
    const float d    = GAMMA * discount[(t + 1) * B_DIM + b];
    const float r    = reward[(t + 1) * B_DIM + b];
    const bool  last = (step_type[t * B_DIM + b] == 2);
    a  = last ? 1.0f : d * a;
    be = last ? 0.0f : fmaf(d, be, r);
    n  = last ? t    : n;
    const int row = t * B_DIM + b;
    alpha[row]  = a;
    beta[row]   = be;
    anchor[row] = n;
  }
}

// ---------------------------------------------------------------------------
// K2: quantile huber loss, full-lane layout.  Each thread owns one (row, j)
// slot; block stages its <=7 ret rows in LDS (reconstructed from alpha/beta/
// anchor + target_value); inner loop over i=0..49 reads ret via ds_read_b128.
// Branch-free pair math (7 VALU):
//   d = ret_i - v_j; c = clamp(d,-1,1); u = |d| - 0.5|c|
//   contrib = u * (0.5*|c| + (tau_j - 0.5)*c)   ==  |tau - (d<0)| * huber(d)
// Per-row sums: <=3 row-segments per wave -> 3 masked butterfly reductions,
// edge rows via global atomicAdd (out pre-zeroed), middle row plain store
// (race-free: a fully-contained middle row is touched by no other wave).
// ---------------------------------------------------------------------------
__global__ void __launch_bounds__(256) loss_kernel(
    const float* __restrict__ value,
    const float* __restrict__ tv,
    const float* __restrict__ alpha,
    const float* __restrict__ beta,
    const int*   __restrict__ anchor,
    float*       __restrict__ out) {
  __shared__ __align__(16) float sret[LROWS * SLOT];

  const int tid  = threadIdx.x;
  const int idx0 = blockIdx.x * 256;
  const int r0   = idx0 / Q_DIM;          // first row this block touches

  // ---- stage ret rows r0..r0+6 into LDS ----
  for (int e = tid; e < LROWS * Q_DIM; e += 256) {
    const int lr  = e / Q_DIM;
    const int i   = e - lr * Q_DIM;
    const int row = r0 + lr;
    if (row < NROW) {
      const int b = row & (B_DIM - 1);
      const int n = anchor[row];
      const float rv =
          fmaf(alpha[row], tv[(n * B_DIM + b) * Q_DIM + i], beta[row]);
      sret[lr * SLOT + i] = rv;
    }
  }
  __syncthreads();

  const int   idx  = idx0 + tid;          // < NPAIR (grid exact)
  const int   row  = idx / Q_DIM;
  const int   j    = idx - row * Q_DIM;
  const int   lr   = row - r0;            // 0..6
  const float v    = value[idx];          // value[t,b,j], coalesced
  const float tm05 = ((float)j + 0.5f) * (1.0f / Q_DIM) - 0.5f;

  const float* rp = &sret[lr * SLOT];
  float s = 0.0f;

  auto pair = [&](float reti) {
    const float d  = reti - v;
    const float c  = fmaxf(-1.0f, fminf(d, 1.0f));        // med3
    const float u  = fmaf(-0.5f, fabsf(c), fabsf(d));     // |d| - 0.5*min(|d|,1)
    const float in = fmaf(0.5f, fabsf(c), tm05 * c);      // 0.5|c| + (tau-.5)c
    s = fmaf(u, in, s);
  };

#pragma unroll
  for (int i0 = 0; i0 < 48; i0 += 4) {
    const float4 rr = *reinterpret_cast<const float4*>(rp + i0);
    pair(rr.x); pair(rr.y); pair(rr.z); pair(rr.w);
  }
  {
    const float2 rr = *reinterpret_cast<const float2*>(rp + 48);
    pair(rr.x); pair(rr.y);
  }

  // ---- per-row reduction: wave spans <=3 row segments ----
  const int r_lo = __builtin_amdgcn_readlane(row, 0);
  const int r_hi = __builtin_amdgcn_readlane(row, 63);
  float s_lo  = (row == r_lo) ? s : 0.0f;
  float s_hi  = (row == r_hi) ? s : 0.0f;
  float s_tot = s;
#pragma unroll
  for (int off = 32; off > 0; off >>= 1) {
    s_lo  += __shfl_xor(s_lo,  off, 64);
    s_hi  += __shfl_xor(s_hi,  off, 64);
    s_tot += __shfl_xor(s_tot, off, 64);
  }

  if ((tid & 63) == 0) {
    const float k = 1.0f / Q_DIM;
    if (r_hi == r_lo) {
      atomicAdd(out + r_lo, s_tot * k);
    } else {
      atomicAdd(out + r_lo, s_lo * k);
      atomicAdd(out + r_hi, s_hi * k);
      if (r_hi > r_lo + 1)                 // middle row fully in this wave
        out[r_lo + 1] = (s_tot - s_lo - s_hi) * k;
    }
  }
}

// ---------------------------------------------------------------------------
extern "C" void kernel_launch(void* const* d_in, const int* in_sizes, int n_in,
                              void* d_out, int out_size, void* d_ws, size_t ws_size,
                              hipStream_t stream) {
  const float* reward       = (const float*)d_in[0];
  const int*   step_type    = (const int*)  d_in[1];
  const float* discount     = (const float*)d_in[2];
  const float* value        = (const float*)d_in[3];
  const float* target_value = (const float*)d_in[4];
  float* out = (float*)d_out;

  float* alpha  = (float*)d_ws;
  float* beta   = alpha + NROW;
  int*   anchor = (int*)(beta + NROW);

  // out rows t<127 are accumulated atomically; row 127 must be zero.
  hipMemsetAsync(out, 0, (size_t)T_DIM * B_DIM * sizeof(float), stream);

  coeff_kernel<<<8, 64, 0, stream>>>(reward, step_type, discount,
                                     alpha, beta, anchor);

  loss_kernel<<<NPAIR / 256, 256, 0, stream>>>(value, target_value,
                                               alpha, beta, anchor, out);
}

// Round 4
// 114.004 us; speedup vs baseline: 1.5933x; 1.5933x over previous
//
#include <hip/hip_runtime.h>

#define GAMMA 0.99f
constexpr int T_DIM = 128;
constexpr int B_DIM = 512;
constexpr int Q_DIM = 50;
constexpr int NROW  = (T_DIM - 1) * B_DIM;   // 65024 loss rows (t<127)
constexpr int NPAIR = NROW * Q_DIM;          // 3251200 = 12700 * 256 exactly
constexpr int SLOT  = 52;                    // LDS row stride (208B, 16B-aligned)
constexpr int LROWS = 7;                     // rows per block: 256 idx can span 7
constexpr int KEEP  = -1;

// ---------------------------------------------------------------------------
// K1: parallel segmented suffix scan of affine maps, one block per b.
// ret[t,b,q] = alpha*tv[anchor,b,q] + beta, where (alpha,beta,anchor) is the
// composite of m_t∘...∘m_126 applied to (a=1,be=0,n=127):
//   m_t: p=last?0:d, qa=last?1:0, qb=last?0:r, nv=last?t:KEEP
//   g∘h: p=p_g*p_h, qa=fma(p_g,qa_h,qa_g), qb=fma(p_g,qb_h,qb_g),
//        nv=(nv_g==KEEP)?nv_h:nv_g
// Hillis-Steele over 128 elements: 7 LDS rounds, zero serial memory chains.
// Output layout [b][128] so stores are coalesced.
// ---------------------------------------------------------------------------
__global__ void __launch_bounds__(128) coeff_kernel(
    const float* __restrict__ reward,
    const int*   __restrict__ step_type,
    const float* __restrict__ discount,
    float* __restrict__ alpha,
    float* __restrict__ beta,
    int*   __restrict__ anchor) {
  __shared__ float sp[128], sqa[128], sqb[128];
  __shared__ int   snv[128];
  const int t = threadIdx.x;
  const int b = blockIdx.x;

  float p, qa, qb; int nv;
  if (t < T_DIM - 1) {
    const bool  last = (step_type[t * B_DIM + b] == 2);
    const float d    = GAMMA * discount[(t + 1) * B_DIM + b];
    const float r    = reward[(t + 1) * B_DIM + b];
    p  = last ? 0.0f : d;
    qa = last ? 1.0f : 0.0f;
    qb = last ? 0.0f : r;
    nv = last ? t    : KEEP;
  } else {                       // t = 127: identity element
    p = 1.0f; qa = 0.0f; qb = 0.0f; nv = KEEP;
  }
  sp[t] = p; sqa[t] = qa; sqb[t] = qb; snv[t] = nv;
  __syncthreads();

#pragma unroll
  for (int off = 1; off < 128; off <<= 1) {
    const bool act = (t + off) < 128;
    float p2 = 1.0f, qa2 = 0.0f, qb2 = 0.0f; int nv2 = KEEP;
    if (act) { p2 = sp[t+off]; qa2 = sqa[t+off]; qb2 = sqb[t+off]; nv2 = snv[t+off]; }
    __syncthreads();
    if (act) {
      qa = fmaf(p, qa2, qa);     // self is the OUTER map (applied last)
      qb = fmaf(p, qb2, qb);
      p  = p * p2;
      nv = (nv == KEEP) ? nv2 : nv;
      sp[t] = p; sqa[t] = qa; sqb[t] = qb; snv[t] = nv;
    }
    __syncthreads();
  }

  if (t < T_DIM - 1) {
    const int row = (b << 7) + t;            // [b][128] layout
    alpha[row]  = p + qa;                    // applied to a-init = 1
    beta[row]   = qb;                        // applied to be-init = 0
    anchor[row] = (nv == KEEP) ? (T_DIM - 1) : nv;
  }
}

// ---------------------------------------------------------------------------
// K2: quantile huber loss, full-lane layout (unchanged verified structure).
// Branch-free pair math (6 VALU with med3):
//   d = ret_i - v_j; c = med3(d,-1,1); u = |d| - 0.5|c|
//   contrib = u * (0.5*|c| + (tau_j - 0.5)*c)   ==  |tau - (d<0)| * huber(d)
// ---------------------------------------------------------------------------
__global__ void __launch_bounds__(256) loss_kernel(
    const float* __restrict__ value,
    const float* __restrict__ tv,
    const float* __restrict__ alpha,
    const float* __restrict__ beta,
    const int*   __restrict__ anchor,
    float*       __restrict__ out) {
  __shared__ __align__(16) float sret[LROWS * SLOT];

  const int tid  = threadIdx.x;
  const int idx0 = blockIdx.x * 256;
  const int r0   = idx0 / Q_DIM;          // first row this block touches

  // ---- stage ret rows r0..r0+6 into LDS ----
  for (int e = tid; e < LROWS * Q_DIM; e += 256) {
    const int lr  = e / Q_DIM;
    const int i   = e - lr * Q_DIM;
    const int row = r0 + lr;
    if (row < NROW) {
      const int b = row & (B_DIM - 1);
      const int t = row >> 9;
      const int ci = (b << 7) + t;        // coeff [b][128] layout (broadcast)
      const int n = anchor[ci];
      const float rv =
          fmaf(alpha[ci], tv[(n * B_DIM + b) * Q_DIM + i], beta[ci]);
      sret[lr * SLOT + i] = rv;
    }
  }
  __syncthreads();

  const int   idx  = idx0 + tid;          // < NPAIR (grid exact)
  const int   row  = idx / Q_DIM;
  const int   j    = idx - row * Q_DIM;
  const int   lr   = row - r0;            // 0..6
  const float v    = value[idx];          // value[t,b,j], coalesced
  const float tm05 = ((float)j + 0.5f) * (1.0f / Q_DIM) - 0.5f;

  const float* rp = &sret[lr * SLOT];
  float s = 0.0f;

  auto pair = [&](float reti) {
    const float d  = reti - v;
    const float c  = __builtin_amdgcn_fmed3f(d, -1.0f, 1.0f);
    const float u  = fmaf(-0.5f, fabsf(c), fabsf(d));     // |d| - 0.5*min(|d|,1)
    const float in = fmaf(0.5f, fabsf(c), tm05 * c);      // 0.5|c| + (tau-.5)c
    s = fmaf(u, in, s);
  };

#pragma unroll
  for (int i0 = 0; i0 < 48; i0 += 4) {
    const float4 rr = *reinterpret_cast<const float4*>(rp + i0);
    pair(rr.x); pair(rr.y); pair(rr.z); pair(rr.w);
  }
  {
    const float2 rr = *reinterpret_cast<const float2*>(rp + 48);
    pair(rr.x); pair(rr.y);
  }

  // ---- per-row reduction: wave spans <=3 row segments ----
  const int r_lo = __builtin_amdgcn_readlane(row, 0);
  const int r_hi = __builtin_amdgcn_readlane(row, 63);
  float s_lo  = (row == r_lo) ? s : 0.0f;
  float s_hi  = (row == r_hi) ? s : 0.0f;
  float s_tot = s;
#pragma unroll
  for (int off = 32; off > 0; off >>= 1) {
    s_lo  += __shfl_xor(s_lo,  off, 64);
    s_hi  += __shfl_xor(s_hi,  off, 64);
    s_tot += __shfl_xor(s_tot, off, 64);
  }

  if ((tid & 63) == 0) {
    const float k = 1.0f / Q_DIM;
    if (r_hi == r_lo) {
      atomicAdd(out + r_lo, s_tot * k);
    } else {
      atomicAdd(out + r_lo, s_lo * k);
      atomicAdd(out + r_hi, s_hi * k);
      if (r_hi > r_lo + 1)                 // middle row fully in this wave
        out[r_lo + 1] = (s_tot - s_lo - s_hi) * k;
    }
  }
}

// ---------------------------------------------------------------------------
extern "C" void kernel_launch(void* const* d_in, const int* in_sizes, int n_in,
                              void* d_out, int out_size, void* d_ws, size_t ws_size,
                              hipStream_t stream) {
  const float* reward       = (const float*)d_in[0];
  const int*   step_type    = (const int*)  d_in[1];
  const float* discount     = (const float*)d_in[2];
  const float* value        = (const float*)d_in[3];
  const float* target_value = (const float*)d_in[4];
  float* out = (float*)d_out;

  float* alpha  = (float*)d_ws;              // [512][128]
  float* beta   = alpha + B_DIM * 128;
  int*   anchor = (int*)(beta + B_DIM * 128);

  // out rows t<127 are accumulated atomically; row 127 must be zero.
  hipMemsetAsync(out, 0, (size_t)T_DIM * B_DIM * sizeof(float), stream);

  coeff_kernel<<<B_DIM, 128, 0, stream>>>(reward, step_type, discount,
                                          alpha, beta, anchor);

  loss_kernel<<<NPAIR / 256, 256, 0, stream>>>(value, target_value,
                                               alpha, beta, anchor, out);
}

// Round 5
// 105.194 us; speedup vs baseline: 1.7268x; 1.0838x over previous
//
#include <hip/hip_runtime.h>

#define GAMMA 0.99f
constexpr int T_DIM = 128;
constexpr int B_DIM = 512;
constexpr int Q_DIM = 50;
constexpr int NROW  = (T_DIM - 1) * B_DIM;   // 65024 loss rows (t<127)
constexpr int SLOT  = 52;                    // LDS row stride (208B, 16B-aligned)
constexpr int R_BLK = 20;                    // ret rows staged per block
constexpr int KEEP  = -1;
constexpr int GRID_LOSS = (NROW + R_BLK - 1) / R_BLK;   // 3252

// ---------------------------------------------------------------------------
// K1: parallel segmented suffix scan of affine maps, one block per b.
// ret[t,b,q] = alpha*tv[anchor,b,q] + beta.  Hillis-Steele over 128 t's:
// 7 LDS rounds, no serial memory chains.  Coeff layout [b][128].
// Thread 127 also writes the required zero at out[127*B+b] (no memset node).
// ---------------------------------------------------------------------------
__global__ void __launch_bounds__(128) coeff_kernel(
    const float* __restrict__ reward,
    const int*   __restrict__ step_type,
    const float* __restrict__ discount,
    float* __restrict__ alpha,
    float* __restrict__ beta,
    int*   __restrict__ anchor,
    float* __restrict__ out) {
  __shared__ float sp[128], sqa[128], sqb[128];
  __shared__ int   snv[128];
  const int t = threadIdx.x;
  const int b = blockIdx.x;

  float p, qa, qb; int nv;
  if (t < T_DIM - 1) {
    const bool  last = (step_type[t * B_DIM + b] == 2);
    const float d    = GAMMA * discount[(t + 1) * B_DIM + b];
    const float r    = reward[(t + 1) * B_DIM + b];
    p  = last ? 0.0f : d;
    qa = last ? 1.0f : 0.0f;
    qb = last ? 0.0f : r;
    nv = last ? t    : KEEP;
  } else {                       // t = 127: identity element
    p = 1.0f; qa = 0.0f; qb = 0.0f; nv = KEEP;
    out[(T_DIM - 1) * B_DIM + b] = 0.0f;     // zero row of the output
  }
  sp[t] = p; sqa[t] = qa; sqb[t] = qb; snv[t] = nv;
  __syncthreads();

#pragma unroll
  for (int off = 1; off < 128; off <<= 1) {
    const bool act = (t + off) < 128;
    float p2 = 1.0f, qa2 = 0.0f, qb2 = 0.0f; int nv2 = KEEP;
    if (act) { p2 = sp[t+off]; qa2 = sqa[t+off]; qb2 = sqb[t+off]; nv2 = snv[t+off]; }
    __syncthreads();
    if (act) {
      qa = fmaf(p, qa2, qa);     // self is the OUTER map (applied last)
      qb = fmaf(p, qb2, qb);
      p  = p * p2;
      nv = (nv == KEEP) ? nv2 : nv;
      sp[t] = p; sqa[t] = qa; sqb[t] = qb; snv[t] = nv;
    }
    __syncthreads();
  }

  if (t < T_DIM - 1) {
    const int row = (b << 7) + t;            // [b][128] layout
    alpha[row]  = p + qa;                    // applied to a-init = 1
    beta[row]   = qb;                        // applied to be-init = 0
    anchor[row] = (nv == KEEP) ? (T_DIM - 1) : nv;
  }
}

// ---------------------------------------------------------------------------
// K2: quantile huber loss.  Block = 256 threads, thread = (r_off=tid/50,
// j=tid%50), 250 active.  Block stages R_BLK=20 ret rows into LDS once
// (1000 elems for 50000 pairs), then 4 row-steps x 50-iter i-loop.
// Branch-free pair math (6 VALU, verified):
//   d = ret_i - v_j; c = med3(d,-1,1); u = |d| - 0.5|c|
//   contrib = u * (0.5*|c| + (tau_j - 0.5)*c)  ==  |tau - (d<0)| * huber(d)
// Per-(row,j) column sums -> LDS pacc -> per-row wave reduce -> plain store.
// No atomics, no memset dependency.
// ---------------------------------------------------------------------------
__global__ void __launch_bounds__(256) loss_kernel(
    const float* __restrict__ value,
    const float* __restrict__ tv,
    const float* __restrict__ alpha,
    const float* __restrict__ beta,
    const int*   __restrict__ anchor,
    float*       __restrict__ out) {
  __shared__ __align__(16) float sret[R_BLK * SLOT];
  __shared__ float pacc[R_BLK * SLOT];

  const int tid = threadIdx.x;
  const int r0  = blockIdx.x * R_BLK;

  // ---- stage ret rows r0..r0+19 into LDS (4 passes of 256 threads) ----
  for (int e = tid; e < R_BLK * Q_DIM; e += 256) {
    const int lr  = e / Q_DIM;
    const int i   = e - lr * Q_DIM;
    const int row = r0 + lr;
    float rv = 0.0f;
    if (row < NROW) {
      const int b  = row & (B_DIM - 1);
      const int t  = row >> 9;
      const int ci = (b << 7) + t;          // coeff [b][128] layout
      const int n  = anchor[ci];
      rv = fmaf(alpha[ci], tv[(n * B_DIM + b) * Q_DIM + i], beta[ci]);
    }
    sret[lr * SLOT + i] = rv;
  }
  __syncthreads();

  const bool act   = tid < 5 * Q_DIM;       // 250 active threads
  const int  r_off = tid / Q_DIM;           // 0..4
  const int  j     = tid - r_off * Q_DIM;
  const float tm05 = ((float)j + 0.5f) * (1.0f / Q_DIM) - 0.5f;

  if (act) {
#pragma unroll
    for (int rb = 0; rb < 4; ++rb) {
      const int lr = rb * 5 + r_off;        // 0..19
      const float* rp = &sret[lr * SLOT];
      // value[(r0+lr)*50 + j] = value[(r0+rb*5)*50 + tid] : fully coalesced.
      // Tail-block overrun stays inside value's t=127 rows (results unused).
      const float v = value[(r0 + rb * 5) * Q_DIM + tid];

      float s = 0.0f;
      auto pair = [&](float reti) {
        const float d  = reti - v;
        const float c  = __builtin_amdgcn_fmed3f(d, -1.0f, 1.0f);
        const float u  = fmaf(-0.5f, fabsf(c), fabsf(d));
        const float in = fmaf(0.5f, fabsf(c), tm05 * c);
        s = fmaf(u, in, s);
      };
#pragma unroll
      for (int i0 = 0; i0 < 48; i0 += 4) {
        const float4 rr = *reinterpret_cast<const float4*>(rp + i0);
        pair(rr.x); pair(rr.y); pair(rr.z); pair(rr.w);
      }
      {
        const float2 rr = *reinterpret_cast<const float2*>(rp + 48);
        pair(rr.x); pair(rr.y);
      }
      pacc[lr * SLOT + j] = s;
    }
  }
  __syncthreads();

  // ---- per-row reduce: wave w handles rows 5w..5w+4 ----
  const int w    = tid >> 6;
  const int lane = tid & 63;
#pragma unroll
  for (int k = 0; k < 5; ++k) {
    const int lr   = w * 5 + k;
    const int grow = r0 + lr;
    float x = (lane < Q_DIM) ? pacc[lr * SLOT + lane] : 0.0f;
#pragma unroll
    for (int off = 32; off > 0; off >>= 1)
      x += __shfl_xor(x, off, 64);
    if (lane == 0 && grow < NROW)
      out[grow] = x * (1.0f / Q_DIM);
  }
}

// ---------------------------------------------------------------------------
extern "C" void kernel_launch(void* const* d_in, const int* in_sizes, int n_in,
                              void* d_out, int out_size, void* d_ws, size_t ws_size,
                              hipStream_t stream) {
  const float* reward       = (const float*)d_in[0];
  const int*   step_type    = (const int*)  d_in[1];
  const float* discount     = (const float*)d_in[2];
  const float* value        = (const float*)d_in[3];
  const float* target_value = (const float*)d_in[4];
  float* out = (float*)d_out;

  float* alpha  = (float*)d_ws;              // [512][128]
  float* beta   = alpha + B_DIM * 128;
  int*   anchor = (int*)(beta + B_DIM * 128);

  coeff_kernel<<<B_DIM, 128, 0, stream>>>(reward, step_type, discount,
                                          alpha, beta, anchor, out);

  loss_kernel<<<GRID_LOSS, 256, 0, stream>>>(value, target_value,
                                             alpha, beta, anchor, out);
}

// Round 6
// 101.487 us; speedup vs baseline: 1.7899x; 1.0365x over previous
//
#include <hip/hip_runtime.h>

#define GAMMA 0.99f
constexpr int T_DIM = 128;
constexpr int B_DIM = 512;
constexpr int Q_DIM = 50;
constexpr int NROW  = (T_DIM - 1) * B_DIM;   // 65024 loss rows (t<127)
constexpr int SLOT  = 52;                    // LDS row stride (208B, 16B-aligned)
constexpr int R_BLK = 20;                    // ret rows staged per block
constexpr int KEEP  = -1;
constexpr int GRID_LOSS = (NROW + R_BLK - 1) / R_BLK;   // 3252

// ---------------------------------------------------------------------------
// K1: parallel segmented suffix scan of affine maps, one block per b.
// ret[t,b,q] = alpha*tv[anchor,b,q] + beta.  Hillis-Steele over 128 t's:
// 7 LDS rounds, no serial memory chains.  Coeff layout [b][128].
// Thread 127 also writes the required zero at out[127*B+b] (no memset node).
// ---------------------------------------------------------------------------
__global__ void __launch_bounds__(128) coeff_kernel(
    const float* __restrict__ reward,
    const int*   __restrict__ step_type,
    const float* __restrict__ discount,
    float* __restrict__ alpha,
    float* __restrict__ beta,
    int*   __restrict__ anchor,
    float* __restrict__ out) {
  __shared__ float sp[128], sqa[128], sqb[128];
  __shared__ int   snv[128];
  const int t = threadIdx.x;
  const int b = blockIdx.x;

  float p, qa, qb; int nv;
  if (t < T_DIM - 1) {
    const bool  last = (step_type[t * B_DIM + b] == 2);
    const float d    = GAMMA * discount[(t + 1) * B_DIM + b];
    const float r    = reward[(t + 1) * B_DIM + b];
    p  = last ? 0.0f : d;
    qa = last ? 1.0f : 0.0f;
    qb = last ? 0.0f : r;
    nv = last ? t    : KEEP;
  } else {                       // t = 127: identity element
    p = 1.0f; qa = 0.0f; qb = 0.0f; nv = KEEP;
    out[(T_DIM - 1) * B_DIM + b] = 0.0f;     // zero row of the output
  }
  sp[t] = p; sqa[t] = qa; sqb[t] = qb; snv[t] = nv;
  __syncthreads();

#pragma unroll
  for (int off = 1; off < 128; off <<= 1) {
    const bool act = (t + off) < 128;
    float p2 = 1.0f, qa2 = 0.0f, qb2 = 0.0f; int nv2 = KEEP;
    if (act) { p2 = sp[t+off]; qa2 = sqa[t+off]; qb2 = sqb[t+off]; nv2 = snv[t+off]; }
    __syncthreads();
    if (act) {
      qa = fmaf(p, qa2, qa);     // self is the OUTER map (applied last)
      qb = fmaf(p, qb2, qb);
      p  = p * p2;
      nv = (nv == KEEP) ? nv2 : nv;
      sp[t] = p; sqa[t] = qa; sqb[t] = qb; snv[t] = nv;
    }
    __syncthreads();
  }

  if (t < T_DIM - 1) {
    const int row = (b << 7) + t;            // [b][128] layout
    alpha[row]  = p + qa;                    // applied to a-init = 1
    beta[row]   = qb;                        // applied to be-init = 0
    anchor[row] = (nv == KEEP) ? (T_DIM - 1) : nv;
  }
}

// ---------------------------------------------------------------------------
// K2: quantile huber loss.  Block = 256 threads, thread = (r_off=tid/50,
// j=tid%50), 250 active.  Block stages R_BLK=20 ret rows into LDS once,
// then 4 row-steps x 50-iter i-loop.
// 5-op pair math (verified identity):
//   d = ret_i - v_j; c = med3(d,-1,1); e = d - 0.5c
//   huber(d) = e*c;  sgn(d)*huber(d) = e*|c|
//   sum_i w*h = 0.5*sum(e*c) + (tau-0.5)*sum(e*|c|)
// tau folded outside the i-loop; abs is a free VOP3 modifier.
// ---------------------------------------------------------------------------
__global__ void __launch_bounds__(256) loss_kernel(
    const float* __restrict__ value,
    const float* __restrict__ tv,
    const float* __restrict__ alpha,
    const float* __restrict__ beta,
    const int*   __restrict__ anchor,
    float*       __restrict__ out) {
  __shared__ __align__(16) float sret[R_BLK * SLOT];
  __shared__ float pacc[R_BLK * SLOT];

  const int tid = threadIdx.x;
  const int r0  = blockIdx.x * R_BLK;

  // ---- stage ret rows r0..r0+19 into LDS (4 passes of 256 threads) ----
  for (int e = tid; e < R_BLK * Q_DIM; e += 256) {
    const int lr  = e / Q_DIM;
    const int i   = e - lr * Q_DIM;
    const int row = r0 + lr;
    float rv = 0.0f;
    if (row < NROW) {
      const int b  = row & (B_DIM - 1);
      const int t  = row >> 9;
      const int ci = (b << 7) + t;          // coeff [b][128] layout
      const int n  = anchor[ci];
      rv = fmaf(alpha[ci], tv[(n * B_DIM + b) * Q_DIM + i], beta[ci]);
    }
    sret[lr * SLOT + i] = rv;
  }
  __syncthreads();

  const bool act   = tid < 5 * Q_DIM;       // 250 active threads
  const int  r_off = tid / Q_DIM;           // 0..4
  const int  j     = tid - r_off * Q_DIM;
  const float tm05 = ((float)j + 0.5f) * (1.0f / Q_DIM) - 0.5f;

  if (act) {
    // hoisted value loads: fully coalesced, issued back-to-back.
    // Tail-block overrun stays inside value's t=127 rows (results unused).
    float vv[4];
#pragma unroll
    for (int rb = 0; rb < 4; ++rb)
      vv[rb] = value[(r0 + rb * 5) * Q_DIM + tid];

#pragma unroll
    for (int rb = 0; rb < 4; ++rb) {
      const int lr = rb * 5 + r_off;        // 0..19
      const float* rp = &sret[lr * SLOT];
      const float v = vv[rb];

      float s1 = 0.0f, s2 = 0.0f;
      auto pair = [&](float reti) {
        const float d = reti - v;
        const float c = __builtin_amdgcn_fmed3f(d, -1.0f, 1.0f);
        const float e = fmaf(-0.5f, c, d);
        s1 = fmaf(e, c, s1);                // sum of huber(d)
        s2 = fmaf(e, fabsf(c), s2);         // sum of sgn(d)*huber(d)
      };
#pragma unroll
      for (int i0 = 0; i0 < 48; i0 += 4) {
        const float4 rr = *reinterpret_cast<const float4*>(rp + i0);
        pair(rr.x); pair(rr.y); pair(rr.z); pair(rr.w);
      }
      {
        const float2 rr = *reinterpret_cast<const float2*>(rp + 48);
        pair(rr.x); pair(rr.y);
      }
      pacc[lr * SLOT + j] = fmaf(tm05, s2, 0.5f * s1);
    }
  }
  __syncthreads();

  // ---- per-row reduce: wave w handles rows 5w..5w+4 ----
  const int w    = tid >> 6;
  const int lane = tid & 63;
#pragma unroll
  for (int k = 0; k < 5; ++k) {
    const int lr   = w * 5 + k;
    const int grow = r0 + lr;
    float x = (lane < Q_DIM) ? pacc[lr * SLOT + lane] : 0.0f;
#pragma unroll
    for (int off = 32; off > 0; off >>= 1)
      x += __shfl_xor(x, off, 64);
    if (lane == 0 && grow < NROW)
      out[grow] = x * (1.0f / Q_DIM);
  }
}

// ---------------------------------------------------------------------------
extern "C" void kernel_launch(void* const* d_in, const int* in_sizes, int n_in,
                              void* d_out, int out_size, void* d_ws, size_t ws_size,
                              hipStream_t stream) {
  const float* reward       = (const float*)d_in[0];
  const int*   step_type    = (const int*)  d_in[1];
  const float* discount     = (const float*)d_in[2];
  const float* value        = (const float*)d_in[3];
  const float* target_value = (const float*)d_in[4];
  float* out = (float*)d_out;

  float* alpha  = (float*)d_ws;              // [512][128]
  float* beta   = alpha + B_DIM * 128;
  int*   anchor = (int*)(beta + B_DIM * 128);

  coeff_kernel<<<B_DIM, 128, 0, stream>>>(reward, step_type, discount,
                                          alpha, beta, anchor, out);

  loss_kernel<<<GRID_LOSS, 256, 0, stream>>>(value, target_value,
                                             alpha, beta, anchor, out);
}